// Round 5
// baseline (5423.352 us; speedup 1.0000x reference)
//
#include <hip/hip_runtime.h>
#include <math.h>

#define HD 64
#define NEGS 0.1f
#define CHUNK 2048
#define ANODES 128
#define AST 68            // padded LDS row stride (floats); 68*4=272B, 16B-aligned
#define AEDGE_CAP 4096

__device__ __forceinline__ float leaky(float v) { return v > 0.f ? v : NEGS * v; }

__global__ void zero_i32(int* __restrict__ p, int n) {
    int i = blockIdx.x * blockDim.x + threadIdx.x;
    int stride = gridDim.x * blockDim.x;
    for (; i < n; i += stride) p[i] = 0;
}

// One wave per node; lane = output feature. 2-layer MLP encoder.
template <int IN>
__global__ void encode_k(const float* __restrict__ x,
                         const float* __restrict__ W1, const float* __restrict__ b1,
                         const float* __restrict__ W2, const float* __restrict__ b2,
                         float* __restrict__ out, int n) {
    __shared__ float sW2[HD * HD];
    for (int idx = threadIdx.x; idx < HD * HD; idx += blockDim.x) sW2[idx] = W2[idx];
    __syncthreads();
    int wave = threadIdx.x >> 6, lane = threadIdx.x & 63;
    int i = blockIdx.x * 4 + wave;
    if (i >= n) return;
    float h1 = b1[lane];
#pragma unroll
    for (int d = 0; d < IN; ++d) h1 += x[i * IN + d] * W1[d * HD + lane];
    h1 = leaky(h1);
    float h2 = b2[lane];
#pragma unroll
    for (int k = 0; k < HD; ++k) {
        float hk = __shfl(h1, k);
        h2 += hk * sW2[k * HD + lane];
    }
    out[i * HD + lane] = leaky(h2);
}

__global__ void gather_k(const float* __restrict__ enc, const int* __restrict__ ptv,
                         float* __restrict__ out, int n) {
    int idx = blockIdx.x * blockDim.x + threadIdx.x;
    int stride = gridDim.x * blockDim.x;
    int total = n * HD;
    for (; idx < total; idx += stride) {
        int i = idx >> 6, j = idx & 63;
        out[idx] = enc[ptv[i] * HD + j];
    }
}

__global__ void hist_k(const int* __restrict__ dst, int* __restrict__ counts, int E_) {
    for (int e = blockIdx.x * blockDim.x + threadIdx.x; e < E_; e += gridDim.x * blockDim.x)
        atomicAdd(&counts[dst[e]], 1);
}

__global__ void scan1(const int* __restrict__ counts, int* __restrict__ bsum, int n) {
    __shared__ int s[256];
    int b = blockIdx.x, t = threadIdx.x;
    int base = b * CHUNK + t * 8;
    int sum = 0;
#pragma unroll
    for (int u = 0; u < 8; ++u) {
        int i = base + u;
        if (i < n) sum += counts[i];
    }
    s[t] = sum;
    __syncthreads();
    for (int off = 128; off > 0; off >>= 1) {
        if (t < off) s[t] += s[t + off];
        __syncthreads();
    }
    if (t == 0) bsum[b] = s[0];
}

__global__ void scan2(int* __restrict__ bsum, int nb, int* __restrict__ row_ptr, int n) {
    if (threadIdx.x == 0 && blockIdx.x == 0) {
        int run = 0;
        for (int b = 0; b < nb; ++b) {
            int v = bsum[b];
            bsum[b] = run;
            run += v;
        }
        row_ptr[n] = run;
    }
}

__global__ void scan3(const int* __restrict__ counts, const int* __restrict__ bsum,
                      int* __restrict__ row_ptr, int* __restrict__ pos, int n) {
    __shared__ int s[256];
    int b = blockIdx.x, t = threadIdx.x;
    int base = b * CHUNK + t * 8;
    int c[8];
    int sum = 0;
#pragma unroll
    for (int u = 0; u < 8; ++u) {
        int i = base + u;
        c[u] = (i < n) ? counts[i] : 0;
        sum += c[u];
    }
    s[t] = sum;
    __syncthreads();
    for (int off = 1; off < 256; off <<= 1) {
        int v = (t >= off) ? s[t - off] : 0;
        __syncthreads();
        s[t] += v;
        __syncthreads();
    }
    int run = bsum[b] + s[t] - sum;  // exclusive prefix for this thread
#pragma unroll
    for (int u = 0; u < 8; ++u) {
        int i = base + u;
        if (i < n) {
            row_ptr[i] = run;
            pos[i] = run;
            run += c[u];
        }
    }
}

__global__ void scatter_k(const int* __restrict__ src, const int* __restrict__ dst,
                          int* __restrict__ pos, int* __restrict__ col, int E_) {
    for (int e = blockIdx.x * blockDim.x + threadIdx.x; e < E_; e += gridDim.x * blockDim.x) {
        int d = dst[e];
        int p = atomicAdd(&pos[d], 1);
        col[p] = src[e];
    }
}

// Edge-parallel segmented aggregation. Block = 128-node CSR chunk (~2048 edges).
// Per-edge local dst precomputed (uchar); 16-lane groups stream contiguous edge
// sub-ranges with 4-deep unrolled 256B row-gathers; LDS atomicAdd into padded
// acc tile; coalesced flush.
__global__ void __launch_bounds__(256) agg_seg(const float* __restrict__ hin,
                                               float* __restrict__ agg,
                                               const int* __restrict__ row_ptr,
                                               const int* __restrict__ col, int n) {
    __shared__ float acc[ANODES * AST];
    __shared__ int srp[ANODES + 1];
    __shared__ unsigned char ldst[AEDGE_CAP];
    int tid = threadIdx.x;
    int c0 = blockIdx.x * ANODES;
    if (c0 >= n) return;
    int nn = n - c0;
    if (nn > ANODES) nn = ANODES;
    for (int i = tid; i <= nn; i += 256) srp[i] = row_ptr[c0 + i];
    for (int i = tid; i < ANODES * AST / 4; i += 256)
        ((float4*)acc)[i] = make_float4(0.f, 0.f, 0.f, 0.f);
    __syncthreads();
    int ebeg = srp[0];
    int ne = srp[nn] - ebeg;
    bool fits = (ne <= AEDGE_CAP);
    if (fits) {
        for (int e = tid; e < ne; e += 256) {
            int ge = ebeg + e;
            int lo = 0, hi = nn;
            while (hi - lo > 1) {
                int mid = (lo + hi) >> 1;
                if (srp[mid] <= ge) lo = mid; else hi = mid;
            }
            ldst[e] = (unsigned char)lo;
        }
    }
    __syncthreads();
    int wid = tid >> 6, lane = tid & 63, g = lane >> 4, s = lane & 15;
    int ws = (int)(((long)ne * wid) >> 2);
    int we = (int)(((long)ne * (wid + 1)) >> 2);
    int wlen = we - ws;
    int gs = ws + (int)(((long)wlen * g) >> 2);
    int gend = ws + (int)(((long)wlen * (g + 1)) >> 2);
    int s4 = s * 4;
    auto findrow = [&](int e) -> int {
        int lo = 0, hi = nn;
        int ge = ebeg + e;
        while (hi - lo > 1) {
            int mid = (lo + hi) >> 1;
            if (srp[mid] <= ge) lo = mid; else hi = mid;
        }
        return lo;
    };
    int k = gs;
    for (; k + 3 < gend; k += 4) {
        int ci0 = col[ebeg + k];
        int ci1 = col[ebeg + k + 1];
        int ci2 = col[ebeg + k + 2];
        int ci3 = col[ebeg + k + 3];
        float4 v0 = ((const float4*)(hin + (size_t)ci0 * HD))[s];
        float4 v1 = ((const float4*)(hin + (size_t)ci1 * HD))[s];
        float4 v2 = ((const float4*)(hin + (size_t)ci2 * HD))[s];
        float4 v3 = ((const float4*)(hin + (size_t)ci3 * HD))[s];
        int d0 = fits ? ldst[k] : findrow(k);
        int d1 = fits ? ldst[k + 1] : findrow(k + 1);
        int d2 = fits ? ldst[k + 2] : findrow(k + 2);
        int d3 = fits ? ldst[k + 3] : findrow(k + 3);
        atomicAdd(&acc[d0 * AST + s4 + 0], v0.x);
        atomicAdd(&acc[d0 * AST + s4 + 1], v0.y);
        atomicAdd(&acc[d0 * AST + s4 + 2], v0.z);
        atomicAdd(&acc[d0 * AST + s4 + 3], v0.w);
        atomicAdd(&acc[d1 * AST + s4 + 0], v1.x);
        atomicAdd(&acc[d1 * AST + s4 + 1], v1.y);
        atomicAdd(&acc[d1 * AST + s4 + 2], v1.z);
        atomicAdd(&acc[d1 * AST + s4 + 3], v1.w);
        atomicAdd(&acc[d2 * AST + s4 + 0], v2.x);
        atomicAdd(&acc[d2 * AST + s4 + 1], v2.y);
        atomicAdd(&acc[d2 * AST + s4 + 2], v2.z);
        atomicAdd(&acc[d2 * AST + s4 + 3], v2.w);
        atomicAdd(&acc[d3 * AST + s4 + 0], v3.x);
        atomicAdd(&acc[d3 * AST + s4 + 1], v3.y);
        atomicAdd(&acc[d3 * AST + s4 + 2], v3.z);
        atomicAdd(&acc[d3 * AST + s4 + 3], v3.w);
    }
    for (; k < gend; ++k) {
        int ci0 = col[ebeg + k];
        float4 v0 = ((const float4*)(hin + (size_t)ci0 * HD))[s];
        int d0 = fits ? ldst[k] : findrow(k);
        atomicAdd(&acc[d0 * AST + s4 + 0], v0.x);
        atomicAdd(&acc[d0 * AST + s4 + 1], v0.y);
        atomicAdd(&acc[d0 * AST + s4 + 2], v0.z);
        atomicAdd(&acc[d0 * AST + s4 + 3], v0.w);
    }
    __syncthreads();
    for (int i = tid; i < nn * (HD / 4); i += 256) {
        int row = i >> 4, c4 = i & 15;
        float4 v = *(float4*)&acc[row * AST + c4 * 4];
        ((float4*)(agg + (size_t)(c0 + row) * HD))[c4] = v;
    }
}

// hout = leaky([agg|h] @ [[Wl],[Wr]] + b). LDS-tiled reg-blocked fp32 GEMM:
// 64-node tile, 256 threads, 4x4 micro-tile. Weights staged ONCE per block,
// block loops over several tiles.
__global__ void __launch_bounds__(256) sage_gemm_tile(const float* __restrict__ agg,
                                                      const float* __restrict__ h,
                                                      float* __restrict__ hout,
                                                      const float* __restrict__ Wl,
                                                      const float* __restrict__ Wr,
                                                      const float* __restrict__ bias, int n) {
    __shared__ float Ws[128][64];   // rows 0..63 = Wl, 64..127 = Wr
    __shared__ float Xs[64][132];   // cols 0..63 = agg row, 64..127 = h row (pad 4)
    int tid = threadIdx.x;
    for (int idx = tid; idx < 64 * 64; idx += 256) {
        int k = idx >> 6, j = idx & 63;
        Ws[k][j] = Wl[idx];
        Ws[64 + k][j] = Wr[idx];
    }
    int tcol = tid & 15, trow = tid >> 4;
    int j0 = tcol * 4;
    float b0 = bias[j0], b1 = bias[j0 + 1], b2 = bias[j0 + 2], b3 = bias[j0 + 3];
    int ntiles = (n + 63) >> 6;
    for (int t = blockIdx.x; t < ntiles; t += gridDim.x) {
        int base = t << 6;
        __syncthreads();  // Xs safe to overwrite (also orders Ws staging on iter 0)
#pragma unroll
        for (int u = 0; u < 8; ++u) {
            int idx = tid + u * 256;   // row = idx>>5, float4-col = idx&31
            int row = idx >> 5, c4 = idx & 31;
            int grow = base + row;
            float4 v = make_float4(0.f, 0.f, 0.f, 0.f);
            if (grow < n) {
                v = (c4 < 16) ? ((const float4*)(agg + (size_t)grow * HD))[c4]
                              : ((const float4*)(h + (size_t)grow * HD))[c4 - 16];
            }
            *(float4*)&Xs[row][c4 * 4] = v;
        }
        __syncthreads();
        float acc[4][4];
#pragma unroll
        for (int r = 0; r < 4; ++r)
#pragma unroll
            for (int c = 0; c < 4; ++c) acc[r][c] = 0.f;
#pragma unroll 4
        for (int k4 = 0; k4 < 32; ++k4) {
            int k = k4 * 4;
            float4 x0 = *(const float4*)&Xs[trow][k];
            float4 x1 = *(const float4*)&Xs[trow + 16][k];
            float4 x2 = *(const float4*)&Xs[trow + 32][k];
            float4 x3 = *(const float4*)&Xs[trow + 48][k];
            float4 w0 = *(const float4*)&Ws[k][j0];
            float4 w1 = *(const float4*)&Ws[k + 1][j0];
            float4 w2 = *(const float4*)&Ws[k + 2][j0];
            float4 w3 = *(const float4*)&Ws[k + 3][j0];
            float4 xr[4] = {x0, x1, x2, x3};
#pragma unroll
            for (int r = 0; r < 4; ++r) {
                acc[r][0] += xr[r].x * w0.x + xr[r].y * w1.x + xr[r].z * w2.x + xr[r].w * w3.x;
                acc[r][1] += xr[r].x * w0.y + xr[r].y * w1.y + xr[r].z * w2.y + xr[r].w * w3.y;
                acc[r][2] += xr[r].x * w0.z + xr[r].y * w1.z + xr[r].z * w2.z + xr[r].w * w3.z;
                acc[r][3] += xr[r].x * w0.w + xr[r].y * w1.w + xr[r].z * w2.w + xr[r].w * w3.w;
            }
        }
#pragma unroll
        for (int r = 0; r < 4; ++r) {
            int grow = base + trow + 16 * r;
            if (grow < n) {
                float4 o;
                o.x = leaky(acc[r][0] + b0);
                o.y = leaky(acc[r][1] + b1);
                o.z = leaky(acc[r][2] + b2);
                o.w = leaky(acc[r][3] + b3);
                *(float4*)(hout + (size_t)grow * HD + j0) = o;
            }
        }
    }
}

// Last layer is rank-1: s_i = h_i . Wl, t_i = h_i . Wr computed first,
// then only SCALARS are aggregated over edges (4B/edge instead of 256B/edge).
__global__ void __launch_bounds__(256) dot_k(const float* __restrict__ h,
                                             const float* __restrict__ Wl,
                                             const float* __restrict__ Wr,
                                             float* __restrict__ sb, float* __restrict__ tb,
                                             int n) {
    int wid = threadIdx.x >> 6, lane = threadIdx.x & 63;
    float wl = Wl[lane], wr = Wr[lane];
    int wpb = blockDim.x >> 6;
    int stride = gridDim.x * wpb;
    for (int i = blockIdx.x * wpb + wid; i < n; i += stride) {
        float hv = h[(size_t)i * HD + lane];
        float a = hv * wl;
        float c = hv * wr;
#pragma unroll
        for (int off = 32; off > 0; off >>= 1) {
            a += __shfl_xor(a, off);
            c += __shfl_xor(c, off);
        }
        if (lane == 0) {
            sb[i] = a;
            tb[i] = c;
        }
    }
}

__global__ void __launch_bounds__(256) last_k(const float* __restrict__ sb,
                                              const float* __restrict__ tb,
                                              const int* __restrict__ row_ptr,
                                              const int* __restrict__ col,
                                              const float* __restrict__ b_last,
                                              float* __restrict__ out, int n) {
    float b0 = b_last[0];
    int stride = gridDim.x * blockDim.x;
    for (int i = blockIdx.x * blockDim.x + threadIdx.x; i < n; i += stride) {
        int beg = row_ptr[i], end = row_ptr[i + 1];
        float acc = 0.f;
        for (int k = beg; k < end; ++k) acc += sb[col[k]];
        out[i] = 1.f / (1.f + expf(-(acc + tb[i] + b0)));
    }
}

extern "C" void kernel_launch(void* const* d_in, const int* in_sizes, int n_in,
                              void* d_out, int out_size, void* d_ws, size_t ws_size,
                              hipStream_t stream) {
    const float* x_gen = (const float*)d_in[0];
    const float* x_load = (const float*)d_in[1];
    const float* x_or = (const float*)d_in[2];
    const float* x_ex = (const float*)d_in[3];
    const int* edge = (const int*)d_in[4];
    const int* ptv = (const int*)d_in[5];
    const float* W_gen1 = (const float*)d_in[6];
    const float* b_gen1 = (const float*)d_in[7];
    const float* W_gen2 = (const float*)d_in[8];
    const float* b_gen2 = (const float*)d_in[9];
    const float* W_load1 = (const float*)d_in[10];
    const float* b_load1 = (const float*)d_in[11];
    const float* W_load2 = (const float*)d_in[12];
    const float* b_load2 = (const float*)d_in[13];
    const float* W_or1 = (const float*)d_in[14];
    const float* b_or1 = (const float*)d_in[15];
    const float* W_or2 = (const float*)d_in[16];
    const float* b_or2 = (const float*)d_in[17];
    const float* W_ex1 = (const float*)d_in[18];
    const float* b_ex1 = (const float*)d_in[19];
    const float* W_ex2 = (const float*)d_in[20];
    const float* b_ex2 = (const float*)d_in[21];
    const float* Wl_h = (const float*)d_in[22];
    const float* Wr_h = (const float*)d_in[23];
    const float* b_h = (const float*)d_in[24];
    const float* Wl_last = (const float*)d_in[25];
    const float* Wr_last = (const float*)d_in[26];
    const float* b_last = (const float*)d_in[27];

    int n_gen = in_sizes[0] / 3;
    int n_load = in_sizes[1] / 3;
    int n_or = in_sizes[2] / 6;
    int n_ex = in_sizes[3] / 6;
    int E_ = in_sizes[4] / 2;
    int N_ = in_sizes[5];
    const int* srcv = edge;        // row 0
    const int* dstv = edge + E_;   // row 1

    char* ws = (char*)d_ws;
    size_t off = 0;
    auto alloc = [&](size_t bytes) -> void* {
        void* p = ws + off;
        off = (off + bytes + 255) & ~(size_t)255;
        return p;
    };
    float* enc = (float*)alloc((size_t)N_ * HD * 4);  // reused as agg after gather
    float* hA = (float*)alloc((size_t)N_ * HD * 4);
    float* hB = (float*)alloc((size_t)N_ * HD * 4);
    int* counts = (int*)alloc((size_t)N_ * 4);
    int* row_ptr = (int*)alloc((size_t)(N_ + 1) * 4);
    int* pos = (int*)alloc((size_t)N_ * 4);
    int* bsum = (int*)alloc(256 * 4);
    int* csr_col = (int*)alloc((size_t)E_ * 4);
    float* sbuf = (float*)alloc((size_t)N_ * 4);
    float* tbuf = (float*)alloc((size_t)N_ * 4);
    float* agg = enc;  // alias: enc is dead after gather_k
    (void)ws_size;

    zero_i32<<<256, 256, 0, stream>>>(counts, N_);

    encode_k<3><<<(n_gen + 3) / 4, 256, 0, stream>>>(x_gen, W_gen1, b_gen1, W_gen2, b_gen2,
                                                     enc, n_gen);
    encode_k<3><<<(n_load + 3) / 4, 256, 0, stream>>>(x_load, W_load1, b_load1, W_load2, b_load2,
                                                      enc + (size_t)n_gen * HD, n_load);
    encode_k<6><<<(n_or + 3) / 4, 256, 0, stream>>>(x_or, W_or1, b_or1, W_or2, b_or2,
                                                    enc + (size_t)(n_gen + n_load) * HD, n_or);
    encode_k<6><<<(n_ex + 3) / 4, 256, 0, stream>>>(x_ex, W_ex1, b_ex1, W_ex2, b_ex2,
                                                    enc + (size_t)(n_gen + n_load + n_or) * HD, n_ex);

    gather_k<<<2048, 256, 0, stream>>>(enc, ptv, hA, N_);

    hist_k<<<2048, 256, 0, stream>>>(dstv, counts, E_);
    int nb = (N_ + CHUNK - 1) / CHUNK;
    scan1<<<nb, 256, 0, stream>>>(counts, bsum, N_);
    scan2<<<1, 64, 0, stream>>>(bsum, nb, row_ptr, N_);
    scan3<<<nb, 256, 0, stream>>>(counts, bsum, row_ptr, pos, N_);
    scatter_k<<<2048, 256, 0, stream>>>(srcv, dstv, pos, csr_col, E_);

    int nchunks = (N_ + ANODES - 1) / ANODES;
    int ntiles = (N_ + 63) >> 6;
    int ggrid = ntiles < 512 ? ntiles : 512;
    float* cur = hA;
    float* nxt = hB;
    for (int l = 0; l < 7; ++l) {
        agg_seg<<<nchunks, 256, 0, stream>>>(cur, agg, row_ptr, csr_col, N_);
        sage_gemm_tile<<<ggrid, 256, 0, stream>>>(agg, cur, nxt,
                                                  Wl_h + (size_t)l * HD * HD,
                                                  Wr_h + (size_t)l * HD * HD,
                                                  b_h + (size_t)l * HD, N_);
        float* t = cur;
        cur = nxt;
        nxt = t;
    }
    dot_k<<<1024, 256, 0, stream>>>(cur, Wl_last, Wr_last, sbuf, tbuf, N_);
    last_k<<<512, 256, 0, stream>>>(sbuf, tbuf, row_ptr, csr_col, b_last,
                                    (float*)d_out, N_);
}

// Round 6
// 922.902 us; speedup vs baseline: 5.8764x; 5.8764x over previous
//
#include <hip/hip_runtime.h>
#include <math.h>

#define HD 64
#define NEGS 0.1f
#define CHUNK 2048
#define NPART 8

__device__ __forceinline__ float leaky(float v) { return v > 0.f ? v : NEGS * v; }

__global__ void zero_i32(int* __restrict__ p, int n) {
    int i = blockIdx.x * blockDim.x + threadIdx.x;
    int stride = gridDim.x * blockDim.x;
    for (; i < n; i += stride) p[i] = 0;
}

// One wave per node; lane = output feature. 2-layer MLP encoder.
template <int IN>
__global__ void encode_k(const float* __restrict__ x,
                         const float* __restrict__ W1, const float* __restrict__ b1,
                         const float* __restrict__ W2, const float* __restrict__ b2,
                         float* __restrict__ out, int n) {
    __shared__ float sW2[HD * HD];
    for (int idx = threadIdx.x; idx < HD * HD; idx += blockDim.x) sW2[idx] = W2[idx];
    __syncthreads();
    int wave = threadIdx.x >> 6, lane = threadIdx.x & 63;
    int i = blockIdx.x * 4 + wave;
    if (i >= n) return;
    float h1 = b1[lane];
#pragma unroll
    for (int d = 0; d < IN; ++d) h1 += x[i * IN + d] * W1[d * HD + lane];
    h1 = leaky(h1);
    float h2 = b2[lane];
#pragma unroll
    for (int k = 0; k < HD; ++k) {
        float hk = __shfl(h1, k);
        h2 += hk * sW2[k * HD + lane];
    }
    out[i * HD + lane] = leaky(h2);
}

__global__ void gather_k(const float* __restrict__ enc, const int* __restrict__ ptv,
                         float* __restrict__ out, int n) {
    int idx = blockIdx.x * blockDim.x + threadIdx.x;
    int stride = gridDim.x * blockDim.x;
    int total = n * HD;
    for (; idx < total; idx += stride) {
        int i = idx >> 6, j = idx & 63;
        out[idx] = enc[ptv[i] * HD + j];
    }
}

// XCD-partitioned histogram: block bid&7 == p handles only dst in partition p
// (aligned with bid%8 -> XCD mapping) so counter atomics stay XCD-local.
__global__ void __launch_bounds__(256) hist_part(const int* __restrict__ dst,
                                                 int* __restrict__ counts,
                                                 int E_, int part_sz) {
    int part = blockIdx.x & (NPART - 1);
    int slice = blockIdx.x >> 3;
    int nslices = gridDim.x >> 3;
    int lo = part * part_sz, hi = lo + part_sz;
    for (int e = slice * blockDim.x + threadIdx.x; e < E_; e += nslices * blockDim.x) {
        int d = dst[e];
        if (d >= lo && d < hi) atomicAdd(&counts[d], 1);
    }
}

__global__ void scan1(const int* __restrict__ counts, int* __restrict__ bsum, int n) {
    __shared__ int s[256];
    int b = blockIdx.x, t = threadIdx.x;
    int base = b * CHUNK + t * 8;
    int sum = 0;
#pragma unroll
    for (int u = 0; u < 8; ++u) {
        int i = base + u;
        if (i < n) sum += counts[i];
    }
    s[t] = sum;
    __syncthreads();
    for (int off = 128; off > 0; off >>= 1) {
        if (t < off) s[t] += s[t + off];
        __syncthreads();
    }
    if (t == 0) bsum[b] = s[0];
}

__global__ void scan2(int* __restrict__ bsum, int nb, int* __restrict__ row_ptr, int n) {
    if (threadIdx.x == 0 && blockIdx.x == 0) {
        int run = 0;
        for (int b = 0; b < nb; ++b) {
            int v = bsum[b];
            bsum[b] = run;
            run += v;
        }
        row_ptr[n] = run;
    }
}

__global__ void scan3(const int* __restrict__ counts, const int* __restrict__ bsum,
                      int* __restrict__ row_ptr, int* __restrict__ pos, int n) {
    __shared__ int s[256];
    int b = blockIdx.x, t = threadIdx.x;
    int base = b * CHUNK + t * 8;
    int c[8];
    int sum = 0;
#pragma unroll
    for (int u = 0; u < 8; ++u) {
        int i = base + u;
        c[u] = (i < n) ? counts[i] : 0;
        sum += c[u];
    }
    s[t] = sum;
    __syncthreads();
    for (int off = 1; off < 256; off <<= 1) {
        int v = (t >= off) ? s[t - off] : 0;
        __syncthreads();
        s[t] += v;
        __syncthreads();
    }
    int run = bsum[b] + s[t] - sum;  // exclusive prefix for this thread
#pragma unroll
    for (int u = 0; u < 8; ++u) {
        int i = base + u;
        if (i < n) {
            row_ptr[i] = run;
            pos[i] = run;
            run += c[u];
        }
    }
}

// XCD-partitioned scatter: all writes to a given csr_col region come from one
// XCD partition -> no cross-XCD dirty-line bouncing (was 107MB WRITE_SIZE).
__global__ void __launch_bounds__(256) scatter_part(const int* __restrict__ src,
                                                    const int* __restrict__ dst,
                                                    int* __restrict__ pos,
                                                    int* __restrict__ col,
                                                    int E_, int part_sz) {
    int part = blockIdx.x & (NPART - 1);
    int slice = blockIdx.x >> 3;
    int nslices = gridDim.x >> 3;
    int lo = part * part_sz, hi = lo + part_sz;
    for (int e = slice * blockDim.x + threadIdx.x; e < E_; e += nslices * blockDim.x) {
        int d = dst[e];
        if (d >= lo && d < hi) {
            int p = atomicAdd(&pos[d], 1);
            col[p] = src[e];
        }
    }
}

// One wave per node. Neighbor indices preloaded with ONE coalesced 64-lane
// load then shfl-broadcast; 4 groups x 16 lanes x float4, 4 streams ->
// up to 16 row-gathers in flight per wave with no address-load dependency.
__global__ void __launch_bounds__(256) agg_k(const float* __restrict__ hin,
                                             float* __restrict__ agg,
                                             const int* __restrict__ row_ptr,
                                             const int* __restrict__ col, int n) {
    int wid = threadIdx.x >> 6, lane = threadIdx.x & 63;
    int g = lane >> 4, s = lane & 15;
    int wpb = blockDim.x >> 6;
    int stride = gridDim.x * wpb;
    for (int i = blockIdx.x * wpb + wid; i < n; i += stride) {
        int beg = row_ptr[i], end = row_ptr[i + 1];
        int deg = end - beg;
        float4 a0 = make_float4(0.f, 0.f, 0.f, 0.f);
        float4 a1 = make_float4(0.f, 0.f, 0.f, 0.f);
        float4 a2 = make_float4(0.f, 0.f, 0.f, 0.f);
        float4 a3 = make_float4(0.f, 0.f, 0.f, 0.f);
        for (int base = 0; base < deg; base += 64) {
            int m = deg - base;
            if (m > 64) m = 64;
            int cidx = (lane < m) ? col[beg + base + lane] : 0;
            int k = g;
            for (; k + 12 < m; k += 16) {
                int c0 = __shfl(cidx, k);
                int c1 = __shfl(cidx, k + 4);
                int c2 = __shfl(cidx, k + 8);
                int c3 = __shfl(cidx, k + 12);
                float4 v0 = ((const float4*)(hin + (size_t)c0 * HD))[s];
                float4 v1 = ((const float4*)(hin + (size_t)c1 * HD))[s];
                float4 v2 = ((const float4*)(hin + (size_t)c2 * HD))[s];
                float4 v3 = ((const float4*)(hin + (size_t)c3 * HD))[s];
                a0.x += v0.x; a0.y += v0.y; a0.z += v0.z; a0.w += v0.w;
                a1.x += v1.x; a1.y += v1.y; a1.z += v1.z; a1.w += v1.w;
                a2.x += v2.x; a2.y += v2.y; a2.z += v2.z; a2.w += v2.w;
                a3.x += v3.x; a3.y += v3.y; a3.z += v3.z; a3.w += v3.w;
            }
            for (; k < m; k += 4) {
                int c0 = __shfl(cidx, k);
                float4 v0 = ((const float4*)(hin + (size_t)c0 * HD))[s];
                a0.x += v0.x; a0.y += v0.y; a0.z += v0.z; a0.w += v0.w;
            }
        }
        a0.x += a1.x + a2.x + a3.x;
        a0.y += a1.y + a2.y + a3.y;
        a0.z += a1.z + a2.z + a3.z;
        a0.w += a1.w + a2.w + a3.w;
        a0.x += __shfl_xor(a0.x, 16);
        a0.y += __shfl_xor(a0.y, 16);
        a0.z += __shfl_xor(a0.z, 16);
        a0.w += __shfl_xor(a0.w, 16);
        a0.x += __shfl_xor(a0.x, 32);
        a0.y += __shfl_xor(a0.y, 32);
        a0.z += __shfl_xor(a0.z, 32);
        a0.w += __shfl_xor(a0.w, 32);
        if (g == 0) ((float4*)(agg + (size_t)i * HD))[s] = a0;
    }
}

// hout = leaky([agg|h] @ [[Wl],[Wr]] + b). LDS-tiled reg-blocked fp32 GEMM:
// 64-node tile, 256 threads, 4x4 micro-tile. Weights staged ONCE per block.
__global__ void __launch_bounds__(256) sage_gemm_tile(const float* __restrict__ agg,
                                                      const float* __restrict__ h,
                                                      float* __restrict__ hout,
                                                      const float* __restrict__ Wl,
                                                      const float* __restrict__ Wr,
                                                      const float* __restrict__ bias, int n) {
    __shared__ float Ws[128][64];   // rows 0..63 = Wl, 64..127 = Wr
    __shared__ float Xs[64][132];   // cols 0..63 = agg row, 64..127 = h row (pad 4)
    int tid = threadIdx.x;
    for (int idx = tid; idx < 64 * 64; idx += 256) {
        int k = idx >> 6, j = idx & 63;
        Ws[k][j] = Wl[idx];
        Ws[64 + k][j] = Wr[idx];
    }
    int tcol = tid & 15, trow = tid >> 4;
    int j0 = tcol * 4;
    float b0 = bias[j0], b1 = bias[j0 + 1], b2 = bias[j0 + 2], b3 = bias[j0 + 3];
    int ntiles = (n + 63) >> 6;
    for (int t = blockIdx.x; t < ntiles; t += gridDim.x) {
        int base = t << 6;
        __syncthreads();  // Xs safe to overwrite (also orders Ws staging on iter 0)
#pragma unroll
        for (int u = 0; u < 8; ++u) {
            int idx = tid + u * 256;   // row = idx>>5, float4-col = idx&31
            int row = idx >> 5, c4 = idx & 31;
            int grow = base + row;
            float4 v = make_float4(0.f, 0.f, 0.f, 0.f);
            if (grow < n) {
                v = (c4 < 16) ? ((const float4*)(agg + (size_t)grow * HD))[c4]
                              : ((const float4*)(h + (size_t)grow * HD))[c4 - 16];
            }
            *(float4*)&Xs[row][c4 * 4] = v;
        }
        __syncthreads();
        float acc[4][4];
#pragma unroll
        for (int r = 0; r < 4; ++r)
#pragma unroll
            for (int c = 0; c < 4; ++c) acc[r][c] = 0.f;
#pragma unroll 4
        for (int k4 = 0; k4 < 32; ++k4) {
            int k = k4 * 4;
            float4 x0 = *(const float4*)&Xs[trow][k];
            float4 x1 = *(const float4*)&Xs[trow + 16][k];
            float4 x2 = *(const float4*)&Xs[trow + 32][k];
            float4 x3 = *(const float4*)&Xs[trow + 48][k];
            float4 w0 = *(const float4*)&Ws[k][j0];
            float4 w1 = *(const float4*)&Ws[k + 1][j0];
            float4 w2 = *(const float4*)&Ws[k + 2][j0];
            float4 w3 = *(const float4*)&Ws[k + 3][j0];
            float4 xr[4] = {x0, x1, x2, x3};
#pragma unroll
            for (int r = 0; r < 4; ++r) {
                acc[r][0] += xr[r].x * w0.x + xr[r].y * w1.x + xr[r].z * w2.x + xr[r].w * w3.x;
                acc[r][1] += xr[r].x * w0.y + xr[r].y * w1.y + xr[r].z * w2.y + xr[r].w * w3.y;
                acc[r][2] += xr[r].x * w0.z + xr[r].y * w1.z + xr[r].z * w2.z + xr[r].w * w3.z;
                acc[r][3] += xr[r].x * w0.w + xr[r].y * w1.w + xr[r].z * w2.w + xr[r].w * w3.w;
            }
        }
#pragma unroll
        for (int r = 0; r < 4; ++r) {
            int grow = base + trow + 16 * r;
            if (grow < n) {
                float4 o;
                o.x = leaky(acc[r][0] + b0);
                o.y = leaky(acc[r][1] + b1);
                o.z = leaky(acc[r][2] + b2);
                o.w = leaky(acc[r][3] + b3);
                *(float4*)(hout + (size_t)grow * HD + j0) = o;
            }
        }
    }
}

// Last layer is rank-1: s_i = h_i . Wl, t_i = h_i . Wr computed first,
// then only SCALARS are aggregated over edges (4B/edge instead of 256B/edge).
__global__ void __launch_bounds__(256) dot_k(const float* __restrict__ h,
                                             const float* __restrict__ Wl,
                                             const float* __restrict__ Wr,
                                             float* __restrict__ sb, float* __restrict__ tb,
                                             int n) {
    int wid = threadIdx.x >> 6, lane = threadIdx.x & 63;
    float wl = Wl[lane], wr = Wr[lane];
    int wpb = blockDim.x >> 6;
    int stride = gridDim.x * wpb;
    for (int i = blockIdx.x * wpb + wid; i < n; i += stride) {
        float hv = h[(size_t)i * HD + lane];
        float a = hv * wl;
        float c = hv * wr;
#pragma unroll
        for (int off = 32; off > 0; off >>= 1) {
            a += __shfl_xor(a, off);
            c += __shfl_xor(c, off);
        }
        if (lane == 0) {
            sb[i] = a;
            tb[i] = c;
        }
    }
}

__global__ void __launch_bounds__(256) last_k(const float* __restrict__ sb,
                                              const float* __restrict__ tb,
                                              const int* __restrict__ row_ptr,
                                              const int* __restrict__ col,
                                              const float* __restrict__ b_last,
                                              float* __restrict__ out, int n) {
    float b0 = b_last[0];
    int stride = gridDim.x * blockDim.x;
    for (int i = blockIdx.x * blockDim.x + threadIdx.x; i < n; i += stride) {
        int beg = row_ptr[i], end = row_ptr[i + 1];
        float acc = 0.f;
        for (int k = beg; k < end; ++k) acc += sb[col[k]];
        out[i] = 1.f / (1.f + expf(-(acc + tb[i] + b0)));
    }
}

extern "C" void kernel_launch(void* const* d_in, const int* in_sizes, int n_in,
                              void* d_out, int out_size, void* d_ws, size_t ws_size,
                              hipStream_t stream) {
    const float* x_gen = (const float*)d_in[0];
    const float* x_load = (const float*)d_in[1];
    const float* x_or = (const float*)d_in[2];
    const float* x_ex = (const float*)d_in[3];
    const int* edge = (const int*)d_in[4];
    const int* ptv = (const int*)d_in[5];
    const float* W_gen1 = (const float*)d_in[6];
    const float* b_gen1 = (const float*)d_in[7];
    const float* W_gen2 = (const float*)d_in[8];
    const float* b_gen2 = (const float*)d_in[9];
    const float* W_load1 = (const float*)d_in[10];
    const float* b_load1 = (const float*)d_in[11];
    const float* W_load2 = (const float*)d_in[12];
    const float* b_load2 = (const float*)d_in[13];
    const float* W_or1 = (const float*)d_in[14];
    const float* b_or1 = (const float*)d_in[15];
    const float* W_or2 = (const float*)d_in[16];
    const float* b_or2 = (const float*)d_in[17];
    const float* W_ex1 = (const float*)d_in[18];
    const float* b_ex1 = (const float*)d_in[19];
    const float* W_ex2 = (const float*)d_in[20];
    const float* b_ex2 = (const float*)d_in[21];
    const float* Wl_h = (const float*)d_in[22];
    const float* Wr_h = (const float*)d_in[23];
    const float* b_h = (const float*)d_in[24];
    const float* Wl_last = (const float*)d_in[25];
    const float* Wr_last = (const float*)d_in[26];
    const float* b_last = (const float*)d_in[27];

    int n_gen = in_sizes[0] / 3;
    int n_load = in_sizes[1] / 3;
    int n_or = in_sizes[2] / 6;
    int n_ex = in_sizes[3] / 6;
    int E_ = in_sizes[4] / 2;
    int N_ = in_sizes[5];
    const int* srcv = edge;        // row 0
    const int* dstv = edge + E_;   // row 1

    char* ws = (char*)d_ws;
    size_t off = 0;
    auto alloc = [&](size_t bytes) -> void* {
        void* p = ws + off;
        off = (off + bytes + 255) & ~(size_t)255;
        return p;
    };
    float* enc = (float*)alloc((size_t)N_ * HD * 4);  // reused as agg after gather
    float* hA = (float*)alloc((size_t)N_ * HD * 4);
    float* hB = (float*)alloc((size_t)N_ * HD * 4);
    int* counts = (int*)alloc((size_t)N_ * 4);
    int* row_ptr = (int*)alloc((size_t)(N_ + 1) * 4);
    int* pos = (int*)alloc((size_t)N_ * 4);
    int* bsum = (int*)alloc(256 * 4);
    int* csr_col = (int*)alloc((size_t)E_ * 4);
    float* sbuf = (float*)alloc((size_t)N_ * 4);
    float* tbuf = (float*)alloc((size_t)N_ * 4);
    float* agg = enc;  // alias: enc is dead after gather_k
    (void)ws_size;

    int part_sz = (N_ + NPART - 1) / NPART;

    zero_i32<<<256, 256, 0, stream>>>(counts, N_);

    encode_k<3><<<(n_gen + 3) / 4, 256, 0, stream>>>(x_gen, W_gen1, b_gen1, W_gen2, b_gen2,
                                                     enc, n_gen);
    encode_k<3><<<(n_load + 3) / 4, 256, 0, stream>>>(x_load, W_load1, b_load1, W_load2, b_load2,
                                                      enc + (size_t)n_gen * HD, n_load);
    encode_k<6><<<(n_or + 3) / 4, 256, 0, stream>>>(x_or, W_or1, b_or1, W_or2, b_or2,
                                                    enc + (size_t)(n_gen + n_load) * HD, n_or);
    encode_k<6><<<(n_ex + 3) / 4, 256, 0, stream>>>(x_ex, W_ex1, b_ex1, W_ex2, b_ex2,
                                                    enc + (size_t)(n_gen + n_load + n_or) * HD, n_ex);

    gather_k<<<2048, 256, 0, stream>>>(enc, ptv, hA, N_);

    hist_part<<<2048, 256, 0, stream>>>(dstv, counts, E_, part_sz);
    int nb = (N_ + CHUNK - 1) / CHUNK;
    scan1<<<nb, 256, 0, stream>>>(counts, bsum, N_);
    scan2<<<1, 64, 0, stream>>>(bsum, nb, row_ptr, N_);
    scan3<<<nb, 256, 0, stream>>>(counts, bsum, row_ptr, pos, N_);
    scatter_part<<<2048, 256, 0, stream>>>(srcv, dstv, pos, csr_col, E_, part_sz);

    int ntiles = (N_ + 63) >> 6;
    int ggrid = ntiles < 512 ? ntiles : 512;
    float* cur = hA;
    float* nxt = hB;
    for (int l = 0; l < 7; ++l) {
        agg_k<<<4096, 256, 0, stream>>>(cur, agg, row_ptr, csr_col, N_);
        sage_gemm_tile<<<ggrid, 256, 0, stream>>>(agg, cur, nxt,
                                                  Wl_h + (size_t)l * HD * HD,
                                                  Wr_h + (size_t)l * HD * HD,
                                                  b_h + (size_t)l * HD, N_);
        float* t = cur;
        cur = nxt;
        nxt = t;
    }
    dot_k<<<1024, 256, 0, stream>>>(cur, Wl_last, Wr_last, sbuf, tbuf, N_);
    last_k<<<512, 256, 0, stream>>>(sbuf, tbuf, row_ptr, csr_col, b_last,
                                    (float*)d_out, N_);
}

// Round 7
// 817.206 us; speedup vs baseline: 6.6365x; 1.1293x over previous
//
#include <hip/hip_runtime.h>
#include <math.h>

#define HD 64
#define NEGS 0.1f
#define CHUNK 2048
#define NPART 8

typedef unsigned short u16;
typedef unsigned int u32;

__device__ __forceinline__ float leaky(float v) { return v > 0.f ? v : NEGS * v; }

// bf16 helpers: storage bf16, compute fp32.
__device__ __forceinline__ u16 f2bf(float f) {
    union { float f; u32 u; } v; v.f = f;
    u32 r = v.u + 0x7FFFu + ((v.u >> 16) & 1u);   // RNE
    return (u16)(r >> 16);
}
__device__ __forceinline__ float bf2f(u16 u) {
    union { u32 i; float f; } v; v.i = ((u32)u) << 16; return v.f;
}
__device__ __forceinline__ float bflo(u32 x) {
    union { u32 i; float f; } v; v.i = x << 16; return v.f;
}
__device__ __forceinline__ float bfhi(u32 x) {
    union { u32 i; float f; } v; v.i = x & 0xFFFF0000u; return v.f;
}
__device__ __forceinline__ u32 pack2(float a, float b) {
    return (u32)f2bf(a) | ((u32)f2bf(b) << 16);
}

__global__ void zero_i32(int* __restrict__ p, int n) {
    int i = blockIdx.x * blockDim.x + threadIdx.x;
    int stride = gridDim.x * blockDim.x;
    for (; i < n; i += stride) p[i] = 0;
}

// One wave per node; lane = output feature. 2-layer MLP encoder. bf16 out.
template <int IN>
__global__ void encode_k(const float* __restrict__ x,
                         const float* __restrict__ W1, const float* __restrict__ b1,
                         const float* __restrict__ W2, const float* __restrict__ b2,
                         u16* __restrict__ out, int n) {
    __shared__ float sW2[HD * HD];
    for (int idx = threadIdx.x; idx < HD * HD; idx += blockDim.x) sW2[idx] = W2[idx];
    __syncthreads();
    int wave = threadIdx.x >> 6, lane = threadIdx.x & 63;
    int i = blockIdx.x * 4 + wave;
    if (i >= n) return;
    float h1 = b1[lane];
#pragma unroll
    for (int d = 0; d < IN; ++d) h1 += x[i * IN + d] * W1[d * HD + lane];
    h1 = leaky(h1);
    float h2 = b2[lane];
#pragma unroll
    for (int k = 0; k < HD; ++k) {
        float hk = __shfl(h1, k);
        h2 += hk * sW2[k * HD + lane];
    }
    out[i * HD + lane] = f2bf(leaky(h2));
}

// bf16 row copy through object_ptv: uint4 = 8 bf16 per thread-chunk.
__global__ void gather_bf(const u16* __restrict__ enc, const int* __restrict__ ptv,
                          u16* __restrict__ out, int n) {
    int idx = blockIdx.x * blockDim.x + threadIdx.x;
    int stride = gridDim.x * blockDim.x;
    int total = n * (HD / 8);
    for (; idx < total; idx += stride) {
        int i = idx >> 3, ch = idx & 7;
        ((uint4*)(out + (size_t)i * HD))[ch] =
            ((const uint4*)(enc + (size_t)ptv[i] * HD))[ch];
    }
}

// XCD-partitioned histogram: block bid&7 == p handles only dst in partition p.
__global__ void __launch_bounds__(256) hist_part(const int* __restrict__ dst,
                                                 int* __restrict__ counts,
                                                 int E_, int part_sz) {
    int part = blockIdx.x & (NPART - 1);
    int slice = blockIdx.x >> 3;
    int nslices = gridDim.x >> 3;
    int lo = part * part_sz, hi = lo + part_sz;
    for (int e = slice * blockDim.x + threadIdx.x; e < E_; e += nslices * blockDim.x) {
        int d = dst[e];
        if (d >= lo && d < hi) atomicAdd(&counts[d], 1);
    }
}

__global__ void scan1(const int* __restrict__ counts, int* __restrict__ bsum, int n) {
    __shared__ int s[256];
    int b = blockIdx.x, t = threadIdx.x;
    int base = b * CHUNK + t * 8;
    int sum = 0;
#pragma unroll
    for (int u = 0; u < 8; ++u) {
        int i = base + u;
        if (i < n) sum += counts[i];
    }
    s[t] = sum;
    __syncthreads();
    for (int off = 128; off > 0; off >>= 1) {
        if (t < off) s[t] += s[t + off];
        __syncthreads();
    }
    if (t == 0) bsum[b] = s[0];
}

__global__ void scan2(int* __restrict__ bsum, int nb, int* __restrict__ row_ptr, int n) {
    if (threadIdx.x == 0 && blockIdx.x == 0) {
        int run = 0;
        for (int b = 0; b < nb; ++b) {
            int v = bsum[b];
            bsum[b] = run;
            run += v;
        }
        row_ptr[n] = run;
    }
}

__global__ void scan3(const int* __restrict__ counts, const int* __restrict__ bsum,
                      int* __restrict__ row_ptr, int* __restrict__ pos, int n) {
    __shared__ int s[256];
    int b = blockIdx.x, t = threadIdx.x;
    int base = b * CHUNK + t * 8;
    int c[8];
    int sum = 0;
#pragma unroll
    for (int u = 0; u < 8; ++u) {
        int i = base + u;
        c[u] = (i < n) ? counts[i] : 0;
        sum += c[u];
    }
    s[t] = sum;
    __syncthreads();
    for (int off = 1; off < 256; off <<= 1) {
        int v = (t >= off) ? s[t - off] : 0;
        __syncthreads();
        s[t] += v;
        __syncthreads();
    }
    int run = bsum[b] + s[t] - sum;  // exclusive prefix for this thread
#pragma unroll
    for (int u = 0; u < 8; ++u) {
        int i = base + u;
        if (i < n) {
            row_ptr[i] = run;
            pos[i] = run;
            run += c[u];
        }
    }
}

// XCD-partitioned scatter: writes to a csr_col region come from one partition.
__global__ void __launch_bounds__(256) scatter_part(const int* __restrict__ src,
                                                    const int* __restrict__ dst,
                                                    int* __restrict__ pos,
                                                    int* __restrict__ col,
                                                    int E_, int part_sz) {
    int part = blockIdx.x & (NPART - 1);
    int slice = blockIdx.x >> 3;
    int nslices = gridDim.x >> 3;
    int lo = part * part_sz, hi = lo + part_sz;
    for (int e = slice * blockDim.x + threadIdx.x; e < E_; e += nslices * blockDim.x) {
        int d = dst[e];
        if (d >= lo && d < hi) {
            int p = atomicAdd(&pos[d], 1);
            col[p] = src[e];
        }
    }
}

// One wave per node, bf16 rows (128B). Indices preloaded coalesced + shfl.
// 4 groups x 16 lanes x uint2(4 bf16), 4 streams; fp32 accumulate.
__global__ void __launch_bounds__(256) agg_bf(const u16* __restrict__ hin,
                                              u16* __restrict__ agg,
                                              const int* __restrict__ row_ptr,
                                              const int* __restrict__ col, int n) {
    int wid = threadIdx.x >> 6, lane = threadIdx.x & 63;
    int g = lane >> 4, s = lane & 15;
    int wpb = blockDim.x >> 6;
    int stride = gridDim.x * wpb;
    for (int i = blockIdx.x * wpb + wid; i < n; i += stride) {
        int beg = row_ptr[i], end = row_ptr[i + 1];
        int deg = end - beg;
        float4 a0 = make_float4(0.f, 0.f, 0.f, 0.f);
        float4 a1 = make_float4(0.f, 0.f, 0.f, 0.f);
        float4 a2 = make_float4(0.f, 0.f, 0.f, 0.f);
        float4 a3 = make_float4(0.f, 0.f, 0.f, 0.f);
        for (int base = 0; base < deg; base += 64) {
            int m = deg - base;
            if (m > 64) m = 64;
            int cidx = (lane < m) ? col[beg + base + lane] : 0;
            int k = g;
            for (; k + 12 < m; k += 16) {
                int c0 = __shfl(cidx, k);
                int c1 = __shfl(cidx, k + 4);
                int c2 = __shfl(cidx, k + 8);
                int c3 = __shfl(cidx, k + 12);
                uint2 v0 = ((const uint2*)(hin + (size_t)c0 * HD))[s];
                uint2 v1 = ((const uint2*)(hin + (size_t)c1 * HD))[s];
                uint2 v2 = ((const uint2*)(hin + (size_t)c2 * HD))[s];
                uint2 v3 = ((const uint2*)(hin + (size_t)c3 * HD))[s];
                a0.x += bflo(v0.x); a0.y += bfhi(v0.x); a0.z += bflo(v0.y); a0.w += bfhi(v0.y);
                a1.x += bflo(v1.x); a1.y += bfhi(v1.x); a1.z += bflo(v1.y); a1.w += bfhi(v1.y);
                a2.x += bflo(v2.x); a2.y += bfhi(v2.x); a2.z += bflo(v2.y); a2.w += bfhi(v2.y);
                a3.x += bflo(v3.x); a3.y += bfhi(v3.x); a3.z += bflo(v3.y); a3.w += bfhi(v3.y);
            }
            for (; k < m; k += 4) {
                int c0 = __shfl(cidx, k);
                uint2 v0 = ((const uint2*)(hin + (size_t)c0 * HD))[s];
                a0.x += bflo(v0.x); a0.y += bfhi(v0.x); a0.z += bflo(v0.y); a0.w += bfhi(v0.y);
            }
        }
        a0.x += a1.x + a2.x + a3.x;
        a0.y += a1.y + a2.y + a3.y;
        a0.z += a1.z + a2.z + a3.z;
        a0.w += a1.w + a2.w + a3.w;
        a0.x += __shfl_xor(a0.x, 16);
        a0.y += __shfl_xor(a0.y, 16);
        a0.z += __shfl_xor(a0.z, 16);
        a0.w += __shfl_xor(a0.w, 16);
        a0.x += __shfl_xor(a0.x, 32);
        a0.y += __shfl_xor(a0.y, 32);
        a0.z += __shfl_xor(a0.z, 32);
        a0.w += __shfl_xor(a0.w, 32);
        if (g == 0) {
            uint2 w;
            w.x = pack2(a0.x, a0.y);
            w.y = pack2(a0.z, a0.w);
            ((uint2*)(agg + (size_t)i * HD))[s] = w;
        }
    }
}

// hout = leaky([agg|h] @ [[Wl],[Wr]] + b). bf16 inputs converted during LDS
// staging; inner loop pure fp32 FMA. 64-node tile, 4x4 micro-tile. bf16 out.
__global__ void __launch_bounds__(256) sage_gemm_bf(const u16* __restrict__ agg,
                                                    const u16* __restrict__ h,
                                                    u16* __restrict__ hout,
                                                    const float* __restrict__ Wl,
                                                    const float* __restrict__ Wr,
                                                    const float* __restrict__ bias, int n) {
    __shared__ float Ws[128][64];   // rows 0..63 = Wl, 64..127 = Wr
    __shared__ float Xs[64][132];   // cols 0..63 = agg row, 64..127 = h row (pad 4)
    int tid = threadIdx.x;
    for (int idx = tid; idx < 64 * 64; idx += 256) {
        int k = idx >> 6, j = idx & 63;
        Ws[k][j] = Wl[idx];
        Ws[64 + k][j] = Wr[idx];
    }
    int tcol = tid & 15, trow = tid >> 4;
    int j0 = tcol * 4;
    float b0 = bias[j0], b1 = bias[j0 + 1], b2 = bias[j0 + 2], b3 = bias[j0 + 3];
    int ntiles = (n + 63) >> 6;
    for (int t = blockIdx.x; t < ntiles; t += gridDim.x) {
        int base = t << 6;
        __syncthreads();  // Xs safe to overwrite
#pragma unroll
        for (int u = 0; u < 4; ++u) {
            int idx = tid + u * 256;   // row = idx>>4, chunk = idx&15 (8 bf16 each)
            int row = idx >> 4, ch = idx & 15;
            int grow = base + row;
            uint4 q = make_uint4(0u, 0u, 0u, 0u);
            if (grow < n) {
                q = (ch < 8) ? ((const uint4*)(agg + (size_t)grow * HD))[ch]
                             : ((const uint4*)(h + (size_t)grow * HD))[ch - 8];
            }
            float* xp = &Xs[row][ch * 8];
            xp[0] = bflo(q.x); xp[1] = bfhi(q.x);
            xp[2] = bflo(q.y); xp[3] = bfhi(q.y);
            xp[4] = bflo(q.z); xp[5] = bfhi(q.z);
            xp[6] = bflo(q.w); xp[7] = bfhi(q.w);
        }
        __syncthreads();
        float acc[4][4];
#pragma unroll
        for (int r = 0; r < 4; ++r)
#pragma unroll
            for (int c = 0; c < 4; ++c) acc[r][c] = 0.f;
#pragma unroll 4
        for (int k4 = 0; k4 < 32; ++k4) {
            int k = k4 * 4;
            float4 x0 = *(const float4*)&Xs[trow][k];
            float4 x1 = *(const float4*)&Xs[trow + 16][k];
            float4 x2 = *(const float4*)&Xs[trow + 32][k];
            float4 x3 = *(const float4*)&Xs[trow + 48][k];
            float4 w0 = *(const float4*)&Ws[k][j0];
            float4 w1 = *(const float4*)&Ws[k + 1][j0];
            float4 w2 = *(const float4*)&Ws[k + 2][j0];
            float4 w3 = *(const float4*)&Ws[k + 3][j0];
            float4 xr[4] = {x0, x1, x2, x3};
#pragma unroll
            for (int r = 0; r < 4; ++r) {
                acc[r][0] += xr[r].x * w0.x + xr[r].y * w1.x + xr[r].z * w2.x + xr[r].w * w3.x;
                acc[r][1] += xr[r].x * w0.y + xr[r].y * w1.y + xr[r].z * w2.y + xr[r].w * w3.y;
                acc[r][2] += xr[r].x * w0.z + xr[r].y * w1.z + xr[r].z * w2.z + xr[r].w * w3.z;
                acc[r][3] += xr[r].x * w0.w + xr[r].y * w1.w + xr[r].z * w2.w + xr[r].w * w3.w;
            }
        }
#pragma unroll
        for (int r = 0; r < 4; ++r) {
            int grow = base + trow + 16 * r;
            if (grow < n) {
                uint2 o;
                o.x = pack2(leaky(acc[r][0] + b0), leaky(acc[r][1] + b1));
                o.y = pack2(leaky(acc[r][2] + b2), leaky(acc[r][3] + b3));
                *(uint2*)(hout + (size_t)grow * HD + j0) = o;
            }
        }
    }
}

// Last layer rank-1: s_i = h_i . Wl, t_i = h_i . Wr; aggregate scalars.
__global__ void __launch_bounds__(256) dot_bf(const u16* __restrict__ h,
                                              const float* __restrict__ Wl,
                                              const float* __restrict__ Wr,
                                              float* __restrict__ sb, float* __restrict__ tb,
                                              int n) {
    int wid = threadIdx.x >> 6, lane = threadIdx.x & 63;
    float wl = Wl[lane], wr = Wr[lane];
    int wpb = blockDim.x >> 6;
    int stride = gridDim.x * wpb;
    for (int i = blockIdx.x * wpb + wid; i < n; i += stride) {
        float hv = bf2f(h[(size_t)i * HD + lane]);
        float a = hv * wl;
        float c = hv * wr;
#pragma unroll
        for (int off = 32; off > 0; off >>= 1) {
            a += __shfl_xor(a, off);
            c += __shfl_xor(c, off);
        }
        if (lane == 0) {
            sb[i] = a;
            tb[i] = c;
        }
    }
}

__global__ void __launch_bounds__(256) last_k(const float* __restrict__ sb,
                                              const float* __restrict__ tb,
                                              const int* __restrict__ row_ptr,
                                              const int* __restrict__ col,
                                              const float* __restrict__ b_last,
                                              float* __restrict__ out, int n) {
    float b0 = b_last[0];
    int stride = gridDim.x * blockDim.x;
    for (int i = blockIdx.x * blockDim.x + threadIdx.x; i < n; i += stride) {
        int beg = row_ptr[i], end = row_ptr[i + 1];
        float acc = 0.f;
        for (int k = beg; k < end; ++k) acc += sb[col[k]];
        out[i] = 1.f / (1.f + expf(-(acc + tb[i] + b0)));
    }
}

extern "C" void kernel_launch(void* const* d_in, const int* in_sizes, int n_in,
                              void* d_out, int out_size, void* d_ws, size_t ws_size,
                              hipStream_t stream) {
    const float* x_gen = (const float*)d_in[0];
    const float* x_load = (const float*)d_in[1];
    const float* x_or = (const float*)d_in[2];
    const float* x_ex = (const float*)d_in[3];
    const int* edge = (const int*)d_in[4];
    const int* ptv = (const int*)d_in[5];
    const float* W_gen1 = (const float*)d_in[6];
    const float* b_gen1 = (const float*)d_in[7];
    const float* W_gen2 = (const float*)d_in[8];
    const float* b_gen2 = (const float*)d_in[9];
    const float* W_load1 = (const float*)d_in[10];
    const float* b_load1 = (const float*)d_in[11];
    const float* W_load2 = (const float*)d_in[12];
    const float* b_load2 = (const float*)d_in[13];
    const float* W_or1 = (const float*)d_in[14];
    const float* b_or1 = (const float*)d_in[15];
    const float* W_or2 = (const float*)d_in[16];
    const float* b_or2 = (const float*)d_in[17];
    const float* W_ex1 = (const float*)d_in[18];
    const float* b_ex1 = (const float*)d_in[19];
    const float* W_ex2 = (const float*)d_in[20];
    const float* b_ex2 = (const float*)d_in[21];
    const float* Wl_h = (const float*)d_in[22];
    const float* Wr_h = (const float*)d_in[23];
    const float* b_h = (const float*)d_in[24];
    const float* Wl_last = (const float*)d_in[25];
    const float* Wr_last = (const float*)d_in[26];
    const float* b_last = (const float*)d_in[27];

    int n_gen = in_sizes[0] / 3;
    int n_load = in_sizes[1] / 3;
    int n_or = in_sizes[2] / 6;
    int n_ex = in_sizes[3] / 6;
    int E_ = in_sizes[4] / 2;
    int N_ = in_sizes[5];
    const int* srcv = edge;        // row 0
    const int* dstv = edge + E_;   // row 1

    char* ws = (char*)d_ws;
    size_t off = 0;
    auto alloc = [&](size_t bytes) -> void* {
        void* p = ws + off;
        off = (off + bytes + 255) & ~(size_t)255;
        return p;
    };
    u16* enc = (u16*)alloc((size_t)N_ * HD * 2);   // reused as agg after gather
    u16* hA = (u16*)alloc((size_t)N_ * HD * 2);
    u16* hB = (u16*)alloc((size_t)N_ * HD * 2);
    int* counts = (int*)alloc((size_t)N_ * 4);
    int* row_ptr = (int*)alloc((size_t)(N_ + 1) * 4);
    int* pos = (int*)alloc((size_t)N_ * 4);
    int* bsum = (int*)alloc(256 * 4);
    int* csr_col = (int*)alloc((size_t)E_ * 4);
    float* sbuf = (float*)alloc((size_t)N_ * 4);
    float* tbuf = (float*)alloc((size_t)N_ * 4);
    u16* agg = enc;  // alias: enc is dead after gather_bf
    (void)ws_size;

    int part_sz = (N_ + NPART - 1) / NPART;

    zero_i32<<<256, 256, 0, stream>>>(counts, N_);

    encode_k<3><<<(n_gen + 3) / 4, 256, 0, stream>>>(x_gen, W_gen1, b_gen1, W_gen2, b_gen2,
                                                     enc, n_gen);
    encode_k<3><<<(n_load + 3) / 4, 256, 0, stream>>>(x_load, W_load1, b_load1, W_load2, b_load2,
                                                      enc + (size_t)n_gen * HD, n_load);
    encode_k<6><<<(n_or + 3) / 4, 256, 0, stream>>>(x_or, W_or1, b_or1, W_or2, b_or2,
                                                    enc + (size_t)(n_gen + n_load) * HD, n_or);
    encode_k<6><<<(n_ex + 3) / 4, 256, 0, stream>>>(x_ex, W_ex1, b_ex1, W_ex2, b_ex2,
                                                    enc + (size_t)(n_gen + n_load + n_or) * HD, n_ex);

    gather_bf<<<1024, 256, 0, stream>>>(enc, ptv, hA, N_);

    hist_part<<<2048, 256, 0, stream>>>(dstv, counts, E_, part_sz);
    int nb = (N_ + CHUNK - 1) / CHUNK;
    scan1<<<nb, 256, 0, stream>>>(counts, bsum, N_);
    scan2<<<1, 64, 0, stream>>>(bsum, nb, row_ptr, N_);
    scan3<<<nb, 256, 0, stream>>>(counts, bsum, row_ptr, pos, N_);
    scatter_part<<<2048, 256, 0, stream>>>(srcv, dstv, pos, csr_col, E_, part_sz);

    int ntiles = (N_ + 63) >> 6;
    int ggrid = ntiles < 512 ? ntiles : 512;
    u16* cur = hA;
    u16* nxt = hB;
    for (int l = 0; l < 7; ++l) {
        agg_bf<<<4096, 256, 0, stream>>>(cur, agg, row_ptr, csr_col, N_);
        sage_gemm_bf<<<ggrid, 256, 0, stream>>>(agg, cur, nxt,
                                                Wl_h + (size_t)l * HD * HD,
                                                Wr_h + (size_t)l * HD * HD,
                                                b_h + (size_t)l * HD, N_);
        u16* t = cur;
        cur = nxt;
        nxt = t;
    }
    dot_bf<<<1024, 256, 0, stream>>>(cur, Wl_last, Wr_last, sbuf, tbuf, N_);
    last_k<<<512, 256, 0, stream>>>(sbuf, tbuf, row_ptr, csr_col, b_last,
                                    (float*)d_out, N_);
}